// Round 4
// baseline (418.891 us; speedup 1.0000x reference)
//
#include <hip/hip_runtime.h>

#define BS 7
#define DROPP 0.1f
#define UH 58
#define UW 58

typedef float f32x4 __attribute__((ext_vector_type(4)));  // native vec: OK for nontemporal builtins

// One block. Bitmask dilation: row i of drop -> 64-bit word; 7x7 max-dilate =
// OR of 7 shifted words (row) then OR of <=7 rows (col). keep-count via popcount.
__global__ __launch_bounds__(1024) void dropblock_mask_kernel(
    const float* __restrict__ u, float* __restrict__ m)
{
    __shared__ unsigned long long sD[64];    // per-row drop bits (rows >=58 zero)
    __shared__ unsigned long long sR[64];    // row-dilated
    __shared__ unsigned long long sDil[64];  // fully dilated
    __shared__ float sscale;

    const int tid  = threadIdx.x;
    const int wave = tid >> 6;   // 0..15
    const int lane = tid & 63;

    // Phase 1: wave w builds rows w, w+16, w+32, w+48 via ballot
    for (int i = wave; i < 64; i += 16) {
        bool d = false;
        if (i < UH && lane < UW) d = (u[i * UW + lane] < DROPP);
        unsigned long long D = __ballot(d);
        if (lane == 0) sD[i] = D;
    }
    __syncthreads();

    // Phase 2: wave 0, lane i: row dilation (6 shifts+ORs)
    if (wave == 0) {
        unsigned long long D = sD[lane];
        unsigned long long R = D;
        #pragma unroll
        for (int s = 1; s <= 6; ++s) R |= (D << s);
        sR[lane] = R;
    }
    __syncthreads();

    // Phase 3: wave 0, lane y: column dilation + popcount + wave-reduce sum
    if (wave == 0) {
        const int y = lane;
        const int i0 = (y - 6 > 0) ? (y - 6) : 0;
        const int i1 = (y < UH - 1) ? y : (UH - 1);
        unsigned long long dil = 0ull;
        for (int i = i0; i <= i1; ++i) dil |= sR[i];
        sDil[y] = dil;
        float kept = (float)(64 - __popcll(dil));
        #pragma unroll
        for (int off = 32; off >= 1; off >>= 1)
            kept += __shfl_down(kept, off, 64);
        if (lane == 0) sscale = 4096.0f / kept;
    }
    __syncthreads();

    // Phase 4: all 1024 threads emit m as one float4 each (coalesced)
    const float s = sscale;
    const unsigned long long dil = sDil[(tid >> 4) & 63]; // y = (4*tid)>>6
    const int xb = (tid * 4) & 63;                        // <= 60, same word
    f32x4 mv;
    mv.x = ((dil >> (xb + 0)) & 1ull) ? 0.0f : s;
    mv.y = ((dil >> (xb + 1)) & 1ull) ? 0.0f : s;
    mv.z = ((dil >> (xb + 2)) & 1ull) ? 0.0f : s;
    mv.w = ((dil >> (xb + 3)) & 1ull) ? 0.0f : s;
    ((f32x4*)m)[tid] = mv;
}

// HBM-bound streaming multiply, 4 float4s (64 B) per thread for MLP.
// base = blockIdx*1024 + tid -> each block covers exactly one 4096-float
// H*W plane; mask index tid + k*256 is block-invariant (L1-resident).
__global__ __launch_bounds__(256) void dropblock_apply_kernel(
    const f32x4* __restrict__ x, const f32x4* __restrict__ m4,
    f32x4* __restrict__ out)
{
    const int tid  = threadIdx.x;
    const int base = blockIdx.x * 1024 + tid;   // float4 units
    f32x4 xv[4], mv[4];
    #pragma unroll
    for (int k = 0; k < 4; ++k) {
        xv[k] = __builtin_nontemporal_load(&x[base + k * 256]);
        mv[k] = m4[tid + k * 256];
    }
    #pragma unroll
    for (int k = 0; k < 4; ++k) {
        f32x4 ov = xv[k] * mv[k];
        __builtin_nontemporal_store(ov, &out[base + k * 256]);
    }
}

extern "C" void kernel_launch(void* const* d_in, const int* in_sizes, int n_in,
                              void* d_out, int out_size, void* d_ws, size_t ws_size,
                              hipStream_t stream) {
    const float* x = (const float*)d_in[0];   // [64,256,64,64] fp32
    const float* u = (const float*)d_in[1];   // [58,58] fp32
    float* out = (float*)d_out;
    float* m   = (float*)d_ws;                // 4096 floats scratch

    dropblock_mask_kernel<<<1, 1024, 0, stream>>>(u, m);

    const int total4 = out_size / 4;          // 16,777,216 float4s
    dropblock_apply_kernel<<<total4 / 1024, 256, 0, stream>>>(
        (const f32x4*)x, (const f32x4*)m, (f32x4*)out);
}